// Round 3
// baseline (872.645 us; speedup 1.0000x reference)
//
#include <hip/hip_runtime.h>
#include <cstdint>
#include <cstddef>

// Problem dims (fixed by the reference).
constexpr int MDIM = 32768;   // B
constexpr int DIN  = 1024;
constexpr int HDIM = 512;
constexpr int LDIM = 64;
constexpr uint32_t BL = (uint32_t)MDIM * (uint32_t)LDIM;  // 2097152

// ---------------------------------------------------------------------------
// Threefry2x32 (JAX-compatible, 20 rounds). Host+device.
// ---------------------------------------------------------------------------
__host__ __device__ __forceinline__ void tf2x32(uint32_t k0, uint32_t k1,
                                                uint32_t x0, uint32_t x1,
                                                uint32_t& o0, uint32_t& o1) {
  const uint32_t k2 = k0 ^ k1 ^ 0x1BD11BDAu;
  x0 += k0; x1 += k1;
#define TFR(r) { x0 += x1; x1 = (x1 << (r)) | (x1 >> (32 - (r))); x1 ^= x0; }
  TFR(13) TFR(15) TFR(26) TFR(6)
  x0 += k1; x1 += k2 + 1u;
  TFR(17) TFR(29) TFR(16) TFR(24)
  x0 += k2; x1 += k0 + 2u;
  TFR(13) TFR(15) TFR(26) TFR(6)
  x0 += k0; x1 += k1 + 3u;
  TFR(17) TFR(29) TFR(16) TFR(24)
  x0 += k1; x1 += k2 + 4u;
  TFR(13) TFR(15) TFR(26) TFR(6)
  x0 += k2; x1 += k0 + 5u;
#undef TFR
  o0 = x0; o1 = x1;
}

// jax_threefry_partitionable=True (default since JAX 0.4.36) random_bits:
// element j of a 32-bit draw gets u64 counter j -> threefry((k0,k1),(hi,lo)),
// 32-bit output = out0 ^ out1.  Here j < 2^25 so hi = 0.
__device__ __forceinline__ uint32_t tf_bits(uint32_t k0, uint32_t k1, uint32_t j) {
  uint32_t o0, o1;
  tf2x32(k0, k1, 0u, j, o0, o1);
  return o0 ^ o1;
}

// ---------------------------------------------------------------------------
// XLA-style Giles erfinv (f32), non-fused to match separate HLO mul/add.
// ---------------------------------------------------------------------------
__device__ __forceinline__ float erfinv_f32(float x) {
  const float xx = __fmul_rn(x, x);
  float w = -log1pf(-xx);
  float p;
  if (w < 5.0f) {
    w = __fadd_rn(w, -2.5f);
    p = 2.81022636e-08f;
    p = __fadd_rn(__fmul_rn(p, w), 3.43273939e-07f);
    p = __fadd_rn(__fmul_rn(p, w), -3.5233877e-06f);
    p = __fadd_rn(__fmul_rn(p, w), -4.39150654e-06f);
    p = __fadd_rn(__fmul_rn(p, w), 0.00021858087f);
    p = __fadd_rn(__fmul_rn(p, w), -0.00125372503f);
    p = __fadd_rn(__fmul_rn(p, w), -0.00417768164f);
    p = __fadd_rn(__fmul_rn(p, w), 0.246640727f);
    p = __fadd_rn(__fmul_rn(p, w), 1.50140941f);
  } else {
    w = __fadd_rn(sqrtf(w), -3.0f);
    p = -0.000200214257f;
    p = __fadd_rn(__fmul_rn(p, w), 0.000100950558f);
    p = __fadd_rn(__fmul_rn(p, w), 0.00134934322f);
    p = __fadd_rn(__fmul_rn(p, w), -0.00367342844f);
    p = __fadd_rn(__fmul_rn(p, w), 0.00573950773f);
    p = __fadd_rn(__fmul_rn(p, w), -0.0076224613f);
    p = __fadd_rn(__fmul_rn(p, w), 0.00943887047f);
    p = __fadd_rn(__fmul_rn(p, w), 1.00167406f);
    p = __fadd_rn(__fmul_rn(p, w), 2.83297682f);
  }
  return __fmul_rn(p, x);
}

// normal-draw constants (match jax.random.normal's uniform(lo=nextafter(-1,0), hi=1))
#define LO_N  (-0x1.fffffep-1f)   /* -(1 - 2^-24) */
#define DIFF_N (2.0f)             /* f32(1 - lo) ties-to-even -> 2.0 */
#define SQRT2_F ((float)1.4142135623730951)
#define DIFF_U (0x1.fffffcp-1f)   /* f32(1.0f - 1e-7f) = 1 - 2^-23 */
#define MINV_U (1e-7f)
#define THIRD_F ((float)(1.0 / 3.0))

// ---------------------------------------------------------------------------
// Marsaglia-Tsang sampler for one element, replicating the JAX K=16 vectorized
// rejection exactly (first accepted proposal; k=0 fallback if all reject).
// ---------------------------------------------------------------------------
__device__ float gamma_sample(float alpha, uint32_t e,
                              uint32_t kz0, uint32_t kz1,
                              uint32_t ku0, uint32_t ku1) {
  const float d = __fsub_rn(alpha, THIRD_F);
  const float c = __fdiv_rn(1.0f, sqrtf(__fmul_rn(9.0f, d)));
  float samp0 = 0.0f;
#pragma unroll 1
  for (int k = 0; k < 16; ++k) {
    const uint32_t j = (uint32_t)k * BL + e;
    const uint32_t zb = tf_bits(kz0, kz1, j);
    const uint32_t ub = tf_bits(ku0, ku1, j);
    // z = sqrt(2) * erfinv(u), u in (lo, 1)
    const float fz = __fsub_rn(__uint_as_float((zb >> 9) | 0x3f800000u), 1.0f);
    float un = __fadd_rn(__fmul_rn(fz, DIFF_N), LO_N);
    un = fmaxf(un, LO_N);
    const float z = __fmul_rn(SQRT2_F, erfinv_f32(un));
    // u ~ Uniform(1e-7, 1)
    const float fu = __fsub_rn(__uint_as_float((ub >> 9) | 0x3f800000u), 1.0f);
    float uu = __fadd_rn(__fmul_rn(fu, DIFF_U), MINV_U);
    uu = fmaxf(uu, MINV_U);
    // v = (1 + c z)^3, integer_pow order: x * (x*x)
    const float t1 = __fadd_rn(1.0f, __fmul_rn(c, z));
    const float v = __fmul_rn(t1, __fmul_rn(t1, t1));
    const bool pos = (v > 0.0f);
    const float sv = pos ? v : 1.0f;
    // b2 = ((0.5*z^2 + d) - d*sv) + d*log(sv)
    const float b2 = __fadd_rn(
        __fsub_rn(__fadd_rn(__fmul_rn(0.5f, __fmul_rn(z, z)), d),
                  __fmul_rn(d, sv)),
        __fmul_rn(d, logf(sv)));
    const float lu = logf(uu);
    const float s = __fmul_rn(d, sv);
    if (k == 0) samp0 = s;
    if (pos && (lu < b2)) return s;
  }
  return samp0;  // argmax(all-false) == 0 -> d * safe_v[0]
}

// ---------------------------------------------------------------------------
// Tiled f32 GEMM + bias + ReLU.  C[M,N] = relu(A[M,K] @ B[K,N] + bias)
// Single accumulator per output, strictly k-ascending fmaf (matches BLAS
// microkernel rounding sequence -> best shot at bit-matching the np ref).
// BM=BN=128, BK=8, TM=TN=8, 256 threads.
// ---------------------------------------------------------------------------
template <int BM, int BN, int BK, int TM, int TN>
__global__ __launch_bounds__(256) void gemm_bias_relu(
    const float* __restrict__ Ap, const float* __restrict__ Bp,
    const float* __restrict__ biasp, float* __restrict__ C,
    int M, int N, int K) {
  constexpr int LDA = BM + 4, LDB = BN + 4;
  __shared__ float As[BK * LDA];
  __shared__ float Bs[BK * LDB];
  const int t = threadIdx.x;
  const int tx = t % (BN / TN);
  const int ty = t / (BN / TN);
  const int bm = blockIdx.y * BM;
  const int bn = blockIdx.x * BN;
  float acc[TM][TN] = {};

  static_assert(BM * BK == 1024 && BK * BN == 1024, "4 elems/thread staging");
  const int aRow = (t * 4) / BK, aCol = (t * 4) % BK;
  const int bRow = (t * 4) / BN, bCol = (t * 4) % BN;

  for (int k0 = 0; k0 < K; k0 += BK) {
    {
      const float4 q = *reinterpret_cast<const float4*>(
          Ap + (size_t)(bm + aRow) * K + (k0 + aCol));
      As[(aCol + 0) * LDA + aRow] = q.x;
      As[(aCol + 1) * LDA + aRow] = q.y;
      As[(aCol + 2) * LDA + aRow] = q.z;
      As[(aCol + 3) * LDA + aRow] = q.w;
    }
    {
      const float4 q = *reinterpret_cast<const float4*>(
          Bp + (size_t)(k0 + bRow) * N + (bn + bCol));
      *reinterpret_cast<float4*>(&Bs[bRow * LDB + bCol]) = q;
    }
    __syncthreads();
#pragma unroll
    for (int k = 0; k < BK; ++k) {
      float a[TM], b[TN];
#pragma unroll
      for (int i = 0; i < TM; ++i) a[i] = As[k * LDA + ty * TM + i];
#pragma unroll
      for (int j = 0; j < TN; ++j) b[j] = Bs[k * LDB + tx * TN + j];
#pragma unroll
      for (int i = 0; i < TM; ++i)
#pragma unroll
        for (int j = 0; j < TN; ++j) acc[i][j] = fmaf(a[i], b[j], acc[i][j]);
    }
    __syncthreads();
  }

  float bv[TN];
#pragma unroll
  for (int j = 0; j < TN; ++j) bv[j] = biasp[bn + tx * TN + j];
#pragma unroll
  for (int i = 0; i < TM; ++i) {
    float o[TN];
#pragma unroll
    for (int j = 0; j < TN; ++j) o[j] = fmaxf(__fadd_rn(acc[i][j], bv[j]), 0.0f);
    float* dst = &C[(size_t)(bm + ty * TM + i) * N + (bn + tx * TN)];
#pragma unroll
    for (int q = 0; q < TN / 4; ++q)
      reinterpret_cast<float4*>(dst)[q] = reinterpret_cast<float4*>(o)[q];
  }
}

// ---------------------------------------------------------------------------
// Layer 3: logits = h2 @ Wl + bl; alpha = softplus(logits)+0.5; gamma sample.
// Writes both outputs (f32) directly.  BM=64, BN=64(=L), BK=16, TM=TN=4.
// ---------------------------------------------------------------------------
__global__ __launch_bounds__(256) void gemm3_sampler(
    const float* __restrict__ A, const float* __restrict__ Wl,
    const float* __restrict__ bl, float* __restrict__ out,
    uint32_t kz0, uint32_t kz1, uint32_t ku0, uint32_t ku1) {
  constexpr int BM = 64, BK = 16, K = 512, N = 64;
  constexpr int LDA = BM + 4, LDB = N + 4;
  __shared__ float As[BK * LDA];
  __shared__ float Bs[BK * LDB];
  const int t = threadIdx.x;
  const int tx = t % 16, ty = t / 16;
  const int bm = blockIdx.x * BM;
  float acc[4][4] = {};
  const int aRow = t / 4, aCol = (t % 4) * 4;   // 64x16 f32 tile, 4/thread
  const int bRow = t / 16, bCol = (t % 16) * 4; // 16x64 f32 tile, 4/thread

  for (int k0 = 0; k0 < K; k0 += BK) {
    {
      const float4 q = *reinterpret_cast<const float4*>(
          A + (size_t)(bm + aRow) * K + (k0 + aCol));
      As[(aCol + 0) * LDA + aRow] = q.x;
      As[(aCol + 1) * LDA + aRow] = q.y;
      As[(aCol + 2) * LDA + aRow] = q.z;
      As[(aCol + 3) * LDA + aRow] = q.w;
    }
    {
      const float4 q = *reinterpret_cast<const float4*>(
          Wl + (size_t)(k0 + bRow) * N + bCol);
      *reinterpret_cast<float4*>(&Bs[bRow * LDB + bCol]) = q;
    }
    __syncthreads();
#pragma unroll
    for (int k = 0; k < BK; ++k) {
      float a[4], b[4];
#pragma unroll
      for (int i = 0; i < 4; ++i) a[i] = As[k * LDA + ty * 4 + i];
#pragma unroll
      for (int j = 0; j < 4; ++j) b[j] = Bs[k * LDB + tx * 4 + j];
#pragma unroll
      for (int i = 0; i < 4; ++i)
#pragma unroll
        for (int j = 0; j < 4; ++j) acc[i][j] = fmaf(a[i], b[j], acc[i][j]);
    }
    __syncthreads();
  }

  float bv[4];
#pragma unroll
  for (int j = 0; j < 4; ++j) bv[j] = bl[tx * 4 + j];

  for (int i = 0; i < 4; ++i) {
    const int row = bm + ty * 4 + i;
    float av[4], sv4[4];
    for (int j = 0; j < 4; ++j) {
      const float x = __fadd_rn(acc[i][j], bv[j]);
      // softplus = logaddexp(x, 0) = max(x,0) + log1p(exp(-|x|)); alpha = +0.5
      const float sp = __fadd_rn(fmaxf(x, 0.0f), log1pf(expf(-fabsf(x))));
      const float alpha = __fadd_rn(sp, 0.5f);
      const uint32_t e = (uint32_t)row * 64u + (uint32_t)(tx * 4 + j);
      const float s = gamma_sample(alpha, e, kz0, kz1, ku0, ku1);
      av[j] = alpha;
      sv4[j] = s;
    }
    *reinterpret_cast<float4*>(&out[(size_t)row * 64 + tx * 4]) =
        *reinterpret_cast<float4*>(av);
    *reinterpret_cast<float4*>(&out[(size_t)BL + (size_t)row * 64 + tx * 4]) =
        *reinterpret_cast<float4*>(sv4);
  }
}

// ---------------------------------------------------------------------------
extern "C" void kernel_launch(void* const* d_in, const int* in_sizes, int n_in,
                              void* d_out, int out_size, void* d_ws, size_t ws_size,
                              hipStream_t stream) {
  (void)in_sizes; (void)n_in; (void)out_size; (void)ws_size;
  const float* x  = (const float*)d_in[0];
  const float* W0 = (const float*)d_in[1];
  const float* b0 = (const float*)d_in[2];
  const float* W1 = (const float*)d_in[3];
  const float* b1 = (const float*)d_in[4];
  const float* Wl = (const float*)d_in[5];
  const float* bl = (const float*)d_in[6];
  float* h1 = (float*)d_ws;                      // 32768x512 f32 = 64 MiB
  float* h2 = h1 + (size_t)MDIM * HDIM;          // another 64 MiB
  float* out = (float*)d_out;                    // [alpha | sample], f32

  // jax.random.split(jax.random.key(1)) under jax_threefry_partitionable:
  // child i = full output pair of threefry2x32(key, (0, i))  (fold_in of iota).
  uint32_t kz0, kz1, ku0, ku1;
  tf2x32(0u, 1u, 0u, 0u, kz0, kz1);
  tf2x32(0u, 1u, 0u, 1u, ku0, ku1);

  dim3 g12(HDIM / 128, MDIM / 128);  // (4, 256)
  gemm_bias_relu<128, 128, 8, 8, 8>
      <<<g12, 256, 0, stream>>>(x, W0, b0, h1, MDIM, HDIM, DIN);
  gemm_bias_relu<128, 128, 8, 8, 8>
      <<<g12, 256, 0, stream>>>(h1, W1, b1, h2, MDIM, HDIM, HDIM);
  gemm3_sampler<<<dim3(MDIM / 64), 256, 0, stream>>>(h2, Wl, bl, out,
                                                     kz0, kz1, ku0, ku1);
}

// Round 4
// 528.898 us; speedup vs baseline: 1.6499x; 1.6499x over previous
//
#include <hip/hip_runtime.h>
#include <cstdint>
#include <cstddef>

typedef __attribute__((ext_vector_type(8))) short short8;
typedef __attribute__((ext_vector_type(4))) float floatx4;

// Problem dims (fixed by the reference).
constexpr int MDIM = 32768;   // B
constexpr int DIN  = 1024;
constexpr int HDIM = 512;
constexpr int LDIM = 64;
constexpr uint32_t BL = (uint32_t)MDIM * (uint32_t)LDIM;  // 2097152

// ---------------------------------------------------------------------------
// Threefry2x32 (JAX-compatible, 20 rounds). Host+device.
// ---------------------------------------------------------------------------
__host__ __device__ __forceinline__ void tf2x32(uint32_t k0, uint32_t k1,
                                                uint32_t x0, uint32_t x1,
                                                uint32_t& o0, uint32_t& o1) {
  const uint32_t k2 = k0 ^ k1 ^ 0x1BD11BDAu;
  x0 += k0; x1 += k1;
#define TFR(r) { x0 += x1; x1 = (x1 << (r)) | (x1 >> (32 - (r))); x1 ^= x0; }
  TFR(13) TFR(15) TFR(26) TFR(6)
  x0 += k1; x1 += k2 + 1u;
  TFR(17) TFR(29) TFR(16) TFR(24)
  x0 += k2; x1 += k0 + 2u;
  TFR(13) TFR(15) TFR(26) TFR(6)
  x0 += k0; x1 += k1 + 3u;
  TFR(17) TFR(29) TFR(16) TFR(24)
  x0 += k1; x1 += k2 + 4u;
  TFR(13) TFR(15) TFR(26) TFR(6)
  x0 += k2; x1 += k0 + 5u;
#undef TFR
  o0 = x0; o1 = x1;
}

// jax_threefry_partitionable random_bits: element j -> counter (0, j), out0^out1.
__device__ __forceinline__ uint32_t tf_bits(uint32_t k0, uint32_t k1, uint32_t j) {
  uint32_t o0, o1;
  tf2x32(k0, k1, 0u, j, o0, o1);
  return o0 ^ o1;
}

// ---------------------------------------------------------------------------
// dtype helpers: f32 <-> bf16 bit tricks (RNE), and 3-way exact split.
// ---------------------------------------------------------------------------
__device__ __forceinline__ float b2f(unsigned short s) {
  return __uint_as_float((uint32_t)s << 16);
}
__device__ __forceinline__ unsigned short f2b(float f) {  // RNE f32 -> bf16
  uint32_t u = __float_as_uint(f);
  u += 0x7fffu + ((u >> 16) & 1u);
  return (unsigned short)(u >> 16);
}
// x = hi + lo + lo2 + r, |r| <= 2^-27 |x| (each subtraction exact).
__device__ __forceinline__ void split3(float x, unsigned short& h,
                                       unsigned short& l, unsigned short& l2) {
  h = f2b(x);
  const float r = __fsub_rn(x, b2f(h));
  l = f2b(r);
  const float r2 = __fsub_rn(r, b2f(l));
  l2 = f2b(r2);
}

// ---------------------------------------------------------------------------
// XLA-style Giles erfinv (f32), non-fused to match separate HLO mul/add.
// ---------------------------------------------------------------------------
__device__ __forceinline__ float erfinv_f32(float x) {
  const float xx = __fmul_rn(x, x);
  float w = -log1pf(-xx);
  float p;
  if (w < 5.0f) {
    w = __fadd_rn(w, -2.5f);
    p = 2.81022636e-08f;
    p = __fadd_rn(__fmul_rn(p, w), 3.43273939e-07f);
    p = __fadd_rn(__fmul_rn(p, w), -3.5233877e-06f);
    p = __fadd_rn(__fmul_rn(p, w), -4.39150654e-06f);
    p = __fadd_rn(__fmul_rn(p, w), 0.00021858087f);
    p = __fadd_rn(__fmul_rn(p, w), -0.00125372503f);
    p = __fadd_rn(__fmul_rn(p, w), -0.00417768164f);
    p = __fadd_rn(__fmul_rn(p, w), 0.246640727f);
    p = __fadd_rn(__fmul_rn(p, w), 1.50140941f);
  } else {
    w = __fadd_rn(sqrtf(w), -3.0f);
    p = -0.000200214257f;
    p = __fadd_rn(__fmul_rn(p, w), 0.000100950558f);
    p = __fadd_rn(__fmul_rn(p, w), 0.00134934322f);
    p = __fadd_rn(__fmul_rn(p, w), -0.00367342844f);
    p = __fadd_rn(__fmul_rn(p, w), 0.00573950773f);
    p = __fadd_rn(__fmul_rn(p, w), -0.0076224613f);
    p = __fadd_rn(__fmul_rn(p, w), 0.00943887047f);
    p = __fadd_rn(__fmul_rn(p, w), 1.00167406f);
    p = __fadd_rn(__fmul_rn(p, w), 2.83297682f);
  }
  return __fmul_rn(p, x);
}

#define LO_N  (-0x1.fffffep-1f)   /* -(1 - 2^-24) */
#define DIFF_N (2.0f)
#define SQRT2_F ((float)1.4142135623730951)
#define DIFF_U (0x1.fffffcp-1f)   /* f32(1.0f - 1e-7f) */
#define MINV_U (1e-7f)
#define THIRD_F ((float)(1.0 / 3.0))

// ---------------------------------------------------------------------------
// Marsaglia-Tsang sampler (JAX K=16 vectorized rejection, first accept).
// ---------------------------------------------------------------------------
__device__ float gamma_sample(float alpha, uint32_t e,
                              uint32_t kz0, uint32_t kz1,
                              uint32_t ku0, uint32_t ku1) {
  const float d = __fsub_rn(alpha, THIRD_F);
  const float c = __fdiv_rn(1.0f, sqrtf(__fmul_rn(9.0f, d)));
  float samp0 = 0.0f;
#pragma unroll 1
  for (int k = 0; k < 16; ++k) {
    const uint32_t j = (uint32_t)k * BL + e;
    const uint32_t zb = tf_bits(kz0, kz1, j);
    const uint32_t ub = tf_bits(ku0, ku1, j);
    const float fz = __fsub_rn(__uint_as_float((zb >> 9) | 0x3f800000u), 1.0f);
    float un = __fadd_rn(__fmul_rn(fz, DIFF_N), LO_N);
    un = fmaxf(un, LO_N);
    const float z = __fmul_rn(SQRT2_F, erfinv_f32(un));
    const float fu = __fsub_rn(__uint_as_float((ub >> 9) | 0x3f800000u), 1.0f);
    float uu = __fadd_rn(__fmul_rn(fu, DIFF_U), MINV_U);
    uu = fmaxf(uu, MINV_U);
    const float t1 = __fadd_rn(1.0f, __fmul_rn(c, z));
    const float v = __fmul_rn(t1, __fmul_rn(t1, t1));
    const bool pos = (v > 0.0f);
    const float sv = pos ? v : 1.0f;
    const float b2 = __fadd_rn(
        __fsub_rn(__fadd_rn(__fmul_rn(0.5f, __fmul_rn(z, z)), d),
                  __fmul_rn(d, sv)),
        __fmul_rn(d, logf(sv)));
    const float lu = logf(uu);
    const float s = __fmul_rn(d, sv);
    if (k == 0) samp0 = s;
    if (pos && (lu < b2)) return s;
  }
  return samp0;
}

// ---------------------------------------------------------------------------
// Prep: split W[K][N] (f32) into 3 bf16 planes, TRANSPOSED to [N][K].
// 32x32 tiles via LDS. Planes at D + p*N*K.
// ---------------------------------------------------------------------------
__global__ __launch_bounds__(256) void split_transpose(
    const float* __restrict__ W, unsigned short* __restrict__ D, int K, int N) {
  __shared__ unsigned short th[32][33], tl[32][33], tl2[32][33];
  const int t = threadIdx.x;
  const int nb = N / 32;
  const int k0 = (blockIdx.x / nb) * 32, n0 = (blockIdx.x % nb) * 32;
#pragma unroll
  for (int i = 0; i < 4; ++i) {
    const int e = i * 256 + t;
    const int kk = e >> 5, nn = e & 31;
    const float x = W[(size_t)(k0 + kk) * N + (n0 + nn)];
    split3(x, th[kk][nn], tl[kk][nn], tl2[kk][nn]);
  }
  __syncthreads();
  const size_t PL = (size_t)N * K;
#pragma unroll
  for (int i = 0; i < 4; ++i) {
    const int e = i * 256 + t;
    const int nn = e >> 5, kk = e & 31;
    const size_t o = (size_t)(n0 + nn) * K + (k0 + kk);
    D[o] = th[kk][nn];
    D[PL + o] = tl[kk][nn];
    D[2 * PL + o] = tl2[kk][nn];
  }
}

// ---------------------------------------------------------------------------
// Split-bf16 MFMA GEMM + bias + ReLU.  C[M,512] = relu(A[M,K] @ B[K,512] + b)
// A: f32, split on the fly into 3 bf16 LDS planes [m][k].
// BT: pre-split bf16 planes [512][K] (k-contig), staged via global_load_lds.
// 6-term product: hh + hl + lh + ll + h*lo2 + lo2*h  (~f32 accuracy).
// 128x128 block, BK=32, 4 waves of 4x4 16x16x32 MFMA tiles.
// ---------------------------------------------------------------------------
template <int K>
__global__ __launch_bounds__(256) void gemm_split_mfma(
    const float* __restrict__ A, const unsigned short* __restrict__ BT,
    const float* __restrict__ bias, float* __restrict__ C) {
  constexpr int N = 512;
  constexpr size_t PL = (size_t)N * K;
  __shared__ unsigned short As[3][128 * 32];
  __shared__ unsigned short Bs[3][128 * 32];
  const int t = threadIdx.x;
  const int lane = t & 63, w = t >> 6;
  const int wm = w >> 1, wn = w & 1;
  const int ln = lane & 15, kq = lane >> 4;
  const int bm = blockIdx.y * 128, bn = blockIdx.x * 128;

  floatx4 acc[4][4];
#pragma unroll
  for (int i = 0; i < 4; ++i)
#pragma unroll
    for (int j = 0; j < 4; ++j) acc[i][j] = (floatx4)0.0f;

  for (int k0 = 0; k0 < K; k0 += 32) {
    // ---- B staging: async 16B direct-to-LDS (planes pre-split) ----
#pragma unroll
    for (int p = 0; p < 3; ++p)
#pragma unroll
      for (int i = 0; i < 2; ++i) {
        const int e = w * 1024 + i * 512 + lane * 8;  // ushort idx in 128x32 tile
        const int n = e >> 5, kc = e & 31;
        const unsigned short* g = BT + p * PL + (size_t)(bn + n) * K + (k0 + kc);
        __builtin_amdgcn_global_load_lds(
            (const __attribute__((address_space(1))) unsigned int*)g,
            (__attribute__((address_space(3))) unsigned int*)&Bs[p][w * 1024 + i * 512],
            16, 0, 0);
      }
    // ---- A staging: f32 load + 3-way split ----
#pragma unroll
    for (int it = 0; it < 4; ++it) {
      const int e4 = (it * 256 + t) * 4;
      const int m = e4 >> 5, kc = e4 & 31;
      const float4 q = *reinterpret_cast<const float4*>(
          &A[(size_t)(bm + m) * K + (k0 + kc)]);
      ushort4 h, l, l2;
      split3(q.x, h.x, l.x, l2.x);
      split3(q.y, h.y, l.y, l2.y);
      split3(q.z, h.z, l.z, l2.z);
      split3(q.w, h.w, l.w, l2.w);
      *reinterpret_cast<ushort4*>(&As[0][m * 32 + kc]) = h;
      *reinterpret_cast<ushort4*>(&As[1][m * 32 + kc]) = l;
      *reinterpret_cast<ushort4*>(&As[2][m * 32 + kc]) = l2;
    }
    __syncthreads();
    // ---- fragments ----
    short8 af[3][4], bf[3][4];
#pragma unroll
    for (int mi = 0; mi < 4; ++mi)
#pragma unroll
      for (int p = 0; p < 3; ++p)
        af[p][mi] = *reinterpret_cast<const short8*>(
            &As[p][(wm * 64 + mi * 16 + ln) * 32 + kq * 8]);
#pragma unroll
    for (int ni = 0; ni < 4; ++ni)
#pragma unroll
      for (int p = 0; p < 3; ++p)
        bf[p][ni] = *reinterpret_cast<const short8*>(
            &Bs[p][(wn * 64 + ni * 16 + ln) * 32 + kq * 8]);
    // ---- 6-term MFMA ----
#pragma unroll
    for (int mi = 0; mi < 4; ++mi)
#pragma unroll
      for (int ni = 0; ni < 4; ++ni) {
        floatx4 a = acc[mi][ni];
        a = __builtin_amdgcn_mfma_f32_16x16x32_bf16(af[0][mi], bf[0][ni], a, 0, 0, 0);
        a = __builtin_amdgcn_mfma_f32_16x16x32_bf16(af[0][mi], bf[1][ni], a, 0, 0, 0);
        a = __builtin_amdgcn_mfma_f32_16x16x32_bf16(af[1][mi], bf[0][ni], a, 0, 0, 0);
        a = __builtin_amdgcn_mfma_f32_16x16x32_bf16(af[1][mi], bf[1][ni], a, 0, 0, 0);
        a = __builtin_amdgcn_mfma_f32_16x16x32_bf16(af[0][mi], bf[2][ni], a, 0, 0, 0);
        a = __builtin_amdgcn_mfma_f32_16x16x32_bf16(af[2][mi], bf[0][ni], a, 0, 0, 0);
        acc[mi][ni] = a;
      }
    __syncthreads();
  }
  // ---- epilogue: bias + ReLU, C/D layout row=kq*4+r, col=ln ----
#pragma unroll
  for (int ni = 0; ni < 4; ++ni) {
    const int n = bn + wn * 64 + ni * 16 + ln;
    const float bb = bias[n];
#pragma unroll
    for (int mi = 0; mi < 4; ++mi)
#pragma unroll
      for (int r = 0; r < 4; ++r) {
        const int m = bm + wm * 64 + mi * 16 + kq * 4 + r;
        C[(size_t)m * N + n] = fmaxf(__fadd_rn(acc[mi][ni][r], bb), 0.0f);
      }
  }
}

// ---------------------------------------------------------------------------
// Layer 3 (f32 vector GEMM, K=512 small) + softplus + sampler. Unchanged.
// ---------------------------------------------------------------------------
__global__ __launch_bounds__(256) void gemm3_sampler(
    const float* __restrict__ A, const float* __restrict__ Wl,
    const float* __restrict__ bl, float* __restrict__ out,
    uint32_t kz0, uint32_t kz1, uint32_t ku0, uint32_t ku1) {
  constexpr int BM = 64, BK = 16, K = 512, N = 64;
  constexpr int LDA = BM + 4, LDB = N + 4;
  __shared__ float Ash[BK * LDA];
  __shared__ float Bsh[BK * LDB];
  const int t = threadIdx.x;
  const int tx = t % 16, ty = t / 16;
  const int bm = blockIdx.x * BM;
  float acc[4][4] = {};
  const int aRow = t / 4, aCol = (t % 4) * 4;
  const int bRow = t / 16, bCol = (t % 16) * 4;

  for (int k0 = 0; k0 < K; k0 += BK) {
    {
      const float4 q = *reinterpret_cast<const float4*>(
          A + (size_t)(bm + aRow) * K + (k0 + aCol));
      Ash[(aCol + 0) * LDA + aRow] = q.x;
      Ash[(aCol + 1) * LDA + aRow] = q.y;
      Ash[(aCol + 2) * LDA + aRow] = q.z;
      Ash[(aCol + 3) * LDA + aRow] = q.w;
    }
    {
      const float4 q = *reinterpret_cast<const float4*>(
          Wl + (size_t)(k0 + bRow) * N + bCol);
      *reinterpret_cast<float4*>(&Bsh[bRow * LDB + bCol]) = q;
    }
    __syncthreads();
#pragma unroll
    for (int k = 0; k < BK; ++k) {
      float a[4], b[4];
#pragma unroll
      for (int i = 0; i < 4; ++i) a[i] = Ash[k * LDA + ty * 4 + i];
#pragma unroll
      for (int j = 0; j < 4; ++j) b[j] = Bsh[k * LDB + tx * 4 + j];
#pragma unroll
      for (int i = 0; i < 4; ++i)
#pragma unroll
        for (int j = 0; j < 4; ++j) acc[i][j] = fmaf(a[i], b[j], acc[i][j]);
    }
    __syncthreads();
  }

  float bv[4];
#pragma unroll
  for (int j = 0; j < 4; ++j) bv[j] = bl[tx * 4 + j];

  for (int i = 0; i < 4; ++i) {
    const int row = bm + ty * 4 + i;
    float av[4], sv4[4];
    for (int j = 0; j < 4; ++j) {
      const float x = __fadd_rn(acc[i][j], bv[j]);
      const float sp = __fadd_rn(fmaxf(x, 0.0f), log1pf(expf(-fabsf(x))));
      const float alpha = __fadd_rn(sp, 0.5f);
      const uint32_t e = (uint32_t)row * 64u + (uint32_t)(tx * 4 + j);
      const float s = gamma_sample(alpha, e, kz0, kz1, ku0, ku1);
      av[j] = alpha;
      sv4[j] = s;
    }
    *reinterpret_cast<float4*>(&out[(size_t)row * 64 + tx * 4]) =
        *reinterpret_cast<float4*>(av);
    *reinterpret_cast<float4*>(&out[(size_t)BL + (size_t)row * 64 + tx * 4]) =
        *reinterpret_cast<float4*>(sv4);
  }
}

// ---------------------------------------------------------------------------
extern "C" void kernel_launch(void* const* d_in, const int* in_sizes, int n_in,
                              void* d_out, int out_size, void* d_ws, size_t ws_size,
                              hipStream_t stream) {
  (void)in_sizes; (void)n_in; (void)out_size; (void)ws_size;
  const float* x  = (const float*)d_in[0];
  const float* W0 = (const float*)d_in[1];
  const float* b0 = (const float*)d_in[2];
  const float* W1 = (const float*)d_in[3];
  const float* b1 = (const float*)d_in[4];
  const float* Wl = (const float*)d_in[5];
  const float* bl = (const float*)d_in[6];
  float* h1 = (float*)d_ws;                      // 32768x512 f32 = 64 MiB
  float* h2 = h1 + (size_t)MDIM * HDIM;          // 64 MiB
  float* out = (float*)d_out;                    // [alpha | sample], f32

  // d_out doubles as early scratch for the pre-split transposed W planes
  // (consumed by gemm1/gemm2, then overwritten by gemm3_sampler's outputs).
  unsigned short* W0T = (unsigned short*)out;           // 3 MiB in alpha region
  unsigned short* W1T = (unsigned short*)(out + BL);    // 1.5 MiB in sample region

  // jax.random.split(jax.random.key(1)) under jax_threefry_partitionable.
  uint32_t kz0, kz1, ku0, ku1;
  tf2x32(0u, 1u, 0u, 0u, kz0, kz1);
  tf2x32(0u, 1u, 0u, 1u, ku0, ku1);

  split_transpose<<<dim3((DIN / 32) * (HDIM / 32)), 256, 0, stream>>>(
      W0, W0T, DIN, HDIM);
  split_transpose<<<dim3((HDIM / 32) * (HDIM / 32)), 256, 0, stream>>>(
      W1, W1T, HDIM, HDIM);

  dim3 g12(HDIM / 128, MDIM / 128);  // (4, 256)
  gemm_split_mfma<DIN><<<g12, 256, 0, stream>>>(x, W0T, b0, h1);
  gemm_split_mfma<HDIM><<<g12, 256, 0, stream>>>(h1, W1T, b1, h2);
  gemm3_sampler<<<dim3(MDIM / 64), 256, 0, stream>>>(h2, Wl, bl, out,
                                                     kz0, kz1, ku0, ku1);
}